// Round 17
// baseline (235.973 us; speedup 1.0000x reference)
//
#include <hip/hip_runtime.h>
#include <hip/hip_bf16.h>

// out[m,b,:] = kv[m,b,:] @ W + bo + query[b,:],  W = (Wo@Wv) row o, col d
// (softmax over size-1 axis == 1 -> ones; q/k/Wq/Wk dead). f32 output.
// K1: Cw = Wo@Wv, MFMA bf16, 64x64 tiles, 256 blocks (~3us, proven r9).
// K2: r15 structure (BK=64, A f32 glds + B bf16 glds, both XOR-swizzled,
//     64x128 tile) + T4: double-buffered LDS with counted vmcnt(8) across
//     RAW s_barriers — next tile's 8 glds stay in flight through compute
//     (r7-r16 diagnosis: every pipe <50% busy; the cost is the per-K-step
//     vmcnt(0) drain __syncthreads forces). No reg-staged loads anywhere in
//     the K-loop -> the r10 asm-island failure mechanism is absent.

typedef __attribute__((ext_vector_type(4))) float f32x4;
typedef __attribute__((ext_vector_type(8))) short short8;

#define D_MODEL 1024
#define BATCH   4096
#define M_ROWS  32768   // 8 * 4096

__device__ __forceinline__ short f2bf(float f) {
    union { float f; unsigned u; } x; x.f = f;
    unsigned r = (x.u + 0x7fffu + ((x.u >> 16) & 1u)) >> 16;   // RNE
    return (short)r;
}

__device__ __forceinline__ unsigned bfpk(float lo, float hi) {
    __hip_bfloat162 h = __float22bfloat162_rn(make_float2(lo, hi));  // v_cvt_pk_bf16_f32
    unsigned u; __builtin_memcpy(&u, &h, 4); return u;
}

__device__ __forceinline__ short8 cvt8(float4 a, float4 b) {
    union { unsigned u[4]; short8 s; } r;
    r.u[0] = bfpk(a.x, a.y);
    r.u[1] = bfpk(a.z, a.w);
    r.u[2] = bfpk(b.x, b.y);
    r.u[3] = bfpk(b.z, b.w);
    return r.s;
}

// ---------------- Kernel 1: fuse weights Cw = Wo @ Wv (bf16, MFMA, 64x64) ----------------
__global__ __launch_bounds__(256) void fuse_w_kernel(
        const float* __restrict__ Wo, const float* __restrict__ Wv,
        short* __restrict__ Cw) {
    __shared__ __align__(16) short Ash[64][32];   // Wo tile  [o][e]
    __shared__ __align__(16) short Bsh[64][32];   // Wv tile transposed: [d][e]
    const int t = threadIdx.x;
    const int lane = t & 63;
    const int w = t >> 6;
    const int wr = w >> 1, wc = w & 1;
    const int brow = blockIdx.y * 64;   // o
    const int bcol = blockIdx.x * 64;   // d

    f32x4 acc[2][2];
#pragma unroll
    for (int m = 0; m < 2; ++m)
#pragma unroll
        for (int n = 0; n < 2; ++n) acc[m][n] = (f32x4)(0.0f);

    for (int kt = 0; kt < 32; ++kt) {
        const float* ga = Wo + (size_t)(brow + (t >> 2)) * D_MODEL + kt * 32 + (t & 3) * 8;
        float4 a0 = *(const float4*)ga;
        float4 a1 = *(const float4*)(ga + 4);
        float4 bv[2];
#pragma unroll
        for (int j = 0; j < 2; ++j) {
            int lin = j * 256 + t;
            int e = lin >> 4, c4 = lin & 15;
            bv[j] = *(const float4*)(Wv + (size_t)(kt * 32 + e) * D_MODEL + bcol + c4 * 4);
        }
        *reinterpret_cast<short8*>(&Ash[t >> 2][(t & 3) * 8]) = cvt8(a0, a1);
#pragma unroll
        for (int j = 0; j < 2; ++j) {
            int lin = j * 256 + t;
            int e = lin >> 4, c4 = lin & 15;
            int d = c4 * 4;
            Bsh[d + 0][e] = f2bf(bv[j].x);
            Bsh[d + 1][e] = f2bf(bv[j].y);
            Bsh[d + 2][e] = f2bf(bv[j].z);
            Bsh[d + 3][e] = f2bf(bv[j].w);
        }
        __syncthreads();
        {
            const int r = lane & 15, q = lane >> 4;
            short8 af[2], bfr[2];
#pragma unroll
            for (int m = 0; m < 2; ++m)
                af[m] = *reinterpret_cast<const short8*>(&Ash[wr * 32 + m * 16 + r][q * 8]);
#pragma unroll
            for (int n = 0; n < 2; ++n)
                bfr[n] = *reinterpret_cast<const short8*>(&Bsh[wc * 32 + n * 16 + r][q * 8]);
#pragma unroll
            for (int m = 0; m < 2; ++m)
#pragma unroll
                for (int n = 0; n < 2; ++n)
                    acc[m][n] = __builtin_amdgcn_mfma_f32_16x16x32_bf16(
                        af[m], bfr[n], acc[m][n], 0, 0, 0);
        }
        __syncthreads();
    }

    const int r = lane & 15, q = lane >> 4;
#pragma unroll
    for (int m = 0; m < 2; ++m)
#pragma unroll
        for (int n = 0; n < 2; ++n)
#pragma unroll
            for (int j = 0; j < 4; ++j) {
                int o = brow + wr * 32 + m * 16 + q * 4 + j;     // C/D: row=(l>>4)*4+j
                int d = bcol + wc * 32 + n * 16 + r;             //      col=l&15
                Cw[(size_t)o * D_MODEL + d] = f2bf(acc[m][n][j]);
            }
}

// ---------------- Kernel 2: BK=64 dbuf + counted vmcnt(8) across raw barriers ----------------
__global__ __launch_bounds__(256, 4) void attn_gemm_kernel(
        const float* __restrict__ kv, const float* __restrict__ query,
        const short* __restrict__ Cw, const float* __restrict__ bo,
        float* __restrict__ out) {
    // A: 64 x 64 f32 (16 chunks of 16B/row), XOR-swizzled via glds SOURCE.
    // B: 128 x 64 bf16 (8 chunks/row), XOR-swizzled via glds SOURCE.
    // Read chunk c of row at position c^(row&7). Double-buffered (64 KB).
    __shared__ __align__(16) float Afs[2][64][64];    // 2 x 16 KB
    __shared__ __align__(16) short Bsh[2][128][64];   // 2 x 16 KB
    const int t = threadIdx.x;
    const int lane = t & 63;
    const int w = t >> 6;
    const int wr = w >> 1, wc = w & 1;
    const int r = lane & 15, q = lane >> 4;

    // XCD swizzle: XCD = L % 8; 8 o-tiles of one row-tile share an XCD ->
    // kv L2-reused 8x (proven r8: FETCH 574->141 MB).
    const int L = blockIdx.x;
    const int x = L & 7, j5 = L >> 3;
    const int bx = j5 & 7;                   // o-tile (0..7)
    const int rt = (j5 >> 3) * 8 + x;        // row-tile (0..511)
    const int brow = rt * 64;

    f32x4 acc[2][4];
#pragma unroll
    for (int m = 0; m < 2; ++m)
#pragma unroll
        for (int n = 0; n < 4; ++n) acc[m][n] = (f32x4)(0.0f);

    auto stage = [&](int kt, int buf) {      // 8 glds issues, no VGPR results
#pragma unroll
        for (int i = 0; i < 4; ++i) {        // A: 16 KB
            int chunk = i * 256 + t;
            int rl = chunk >> 4, d = chunk & 15;
            int cs = d ^ (rl & 7);
            const float* g = kv + (size_t)(brow + rl) * D_MODEL + kt * 64 + cs * 4;
            __builtin_amdgcn_global_load_lds(
                (const __attribute__((address_space(1))) void*)g,
                (__attribute__((address_space(3))) void*)
                    ((char*)&Afs[buf][0][0] + i * 4096 + w * 1024),
                16, 0, 0);
        }
#pragma unroll
        for (int i = 0; i < 4; ++i) {        // B: 16 KB
            int chunk = i * 256 + t;
            int rl = chunk >> 3, d = chunk & 7;
            int cs = d ^ (rl & 7);
            const short* g = Cw + (size_t)(bx * 128 + rl) * D_MODEL + kt * 64 + cs * 8;
            __builtin_amdgcn_global_load_lds(
                (const __attribute__((address_space(1))) void*)g,
                (__attribute__((address_space(3))) void*)
                    ((char*)&Bsh[buf][0][0] + i * 4096 + w * 1024),
                16, 0, 0);
        }
    };
    auto compute = [&](int buf) {
#pragma unroll
        for (int s = 0; s < 2; ++s) {
            short8 af[2], bfr[4];
#pragma unroll
            for (int m = 0; m < 2; ++m) {
                int row = wr * 32 + m * 16 + r;
                int c0 = (s * 8 + q * 2) ^ (row & 7);
                int c1 = (s * 8 + q * 2 + 1) ^ (row & 7);
                float4 lo = *(const float4*)&Afs[buf][row][c0 * 4];
                float4 hi = *(const float4*)&Afs[buf][row][c1 * 4];
                af[m] = cvt8(lo, hi);                 // pk cvt under MFMA
            }
#pragma unroll
            for (int n = 0; n < 4; ++n) {
                int row = wc * 64 + n * 16 + r;
                int c = (s * 4 + q) ^ (row & 7);
                bfr[n] = *reinterpret_cast<const short8*>(&Bsh[buf][row][c * 8]);
            }
#pragma unroll
            for (int m = 0; m < 2; ++m)
#pragma unroll
                for (int n = 0; n < 4; ++n)
                    acc[m][n] = __builtin_amdgcn_mfma_f32_16x16x32_bf16(
                        af[m], bfr[n], acc[m][n], 0, 0, 0);
        }
    };

    // prologue: tile 0 -> buf 0 (8 glds in flight)
    stage(0, 0);
    for (int kt = 0; kt < 16; ++kt) {
        const int cur = kt & 1;
        if (kt < 15) {
            stage(kt + 1, cur ^ 1);          // 8 more in flight (16 total)
            asm volatile("s_waitcnt vmcnt(8)" ::: "memory");  // cur's 8 landed
        } else {
            asm volatile("s_waitcnt vmcnt(0)" ::: "memory");  // drain last
        }
        __builtin_amdgcn_s_barrier();        // all waves' cur-writes visible
        compute(cur);                        // next tile's glds still flying
        __builtin_amdgcn_s_barrier();        // reads done before overwrite
    }

    // epilogue: + bo + query residual, f32 store
#pragma unroll
    for (int n = 0; n < 4; ++n) {
        int o = bx * 128 + wc * 64 + n * 16 + r;
        float bov = bo[o];
#pragma unroll
        for (int m = 0; m < 2; ++m) {
            int gb = brow + wr * 32 + m * 16 + q * 4;
#pragma unroll
            for (int j = 0; j < 4; ++j) {
                int grow = gb + j;
                out[(size_t)grow * D_MODEL + o] =
                    acc[m][n][j] + bov +
                    query[(size_t)(grow & (BATCH - 1)) * D_MODEL + o];
            }
        }
    }
}

extern "C" void kernel_launch(void* const* d_in, const int* in_sizes, int n_in,
                              void* d_out, int out_size, void* d_ws, size_t ws_size,
                              hipStream_t stream) {
    // Robust input classification by element count (falls back to dict order):
    int kv_i = 1, q_i = 0, bo_i = 6;
    int w_i[4] = {2, 3, 4, 5};
    int nw = 0;
    for (int i = 0; i < n_in; ++i) {
        long s = in_sizes[i];
        if (s == 33554432) kv_i = i;
        else if (s == 4194304) q_i = i;
        else if (s == 1024) bo_i = i;
        else if (s == 1048576 && nw < 4) w_i[nw++] = i;
    }
    const float* query = (const float*)d_in[q_i];
    const float* kv    = (const float*)d_in[kv_i];
    const float* Wv    = (const float*)d_in[w_i[2]];
    const float* Wo    = (const float*)d_in[w_i[3]];
    const float* bo    = (const float*)d_in[bo_i];
    short* Cw  = (short*)d_ws;              // 1024*1024 bf16 = 2 MB
    float* out = (float*)d_out;             // f32 output

    fuse_w_kernel<<<dim3(16, 16), dim3(256), 0, stream>>>(Wo, Wv, Cw);
    attn_gemm_kernel<<<dim3(4096), dim3(256), 0, stream>>>(kv, query, Cw, bo, out);
}

// Round 18
// 217.846 us; speedup vs baseline: 1.0832x; 1.0832x over previous
//
#include <hip/hip_runtime.h>
#include <hip/hip_bf16.h>

// out[m,b,:] = kv[m,b,:] @ W + bo + query[b,:],  W = (Wo@Wv) row o, col d
// (softmax over size-1 axis == 1 -> ones; q/k/Wq/Wk dead). f32 output.
// K1: Cw = Wo@Wv, MFMA bf16, 64x64 tiles, 256 blocks (~3us, proven r9).
// K2: 128x128 tile / BK=64 / 8 waves (2x4): doubles MFMA-per-exposure vs
//     r15's 64x128 (the one knob never scaled; every pipe <=65% across
//     r13-r17) while acc stays 32 VGPR/wave -> high occupancy. All staging
//     components proven: f32-A glds + bf16-B glds, both-sides XOR swizzle
//     (0-conflict algebra, r16), 2-barrier loop, XCD swizzle (r8).

typedef __attribute__((ext_vector_type(4))) float f32x4;
typedef __attribute__((ext_vector_type(8))) short short8;

#define D_MODEL 1024
#define BATCH   4096
#define M_ROWS  32768   // 8 * 4096

__device__ __forceinline__ short f2bf(float f) {
    union { float f; unsigned u; } x; x.f = f;
    unsigned r = (x.u + 0x7fffu + ((x.u >> 16) & 1u)) >> 16;   // RNE
    return (short)r;
}

__device__ __forceinline__ unsigned bfpk(float lo, float hi) {
    __hip_bfloat162 h = __float22bfloat162_rn(make_float2(lo, hi));  // v_cvt_pk_bf16_f32
    unsigned u; __builtin_memcpy(&u, &h, 4); return u;
}

__device__ __forceinline__ short8 cvt8(float4 a, float4 b) {
    union { unsigned u[4]; short8 s; } r;
    r.u[0] = bfpk(a.x, a.y);
    r.u[1] = bfpk(a.z, a.w);
    r.u[2] = bfpk(b.x, b.y);
    r.u[3] = bfpk(b.z, b.w);
    return r.s;
}

// ---------------- Kernel 1: fuse weights Cw = Wo @ Wv (bf16, MFMA, 64x64) ----------------
__global__ __launch_bounds__(256) void fuse_w_kernel(
        const float* __restrict__ Wo, const float* __restrict__ Wv,
        short* __restrict__ Cw) {
    __shared__ __align__(16) short Ash[64][32];   // Wo tile  [o][e]
    __shared__ __align__(16) short Bsh[64][32];   // Wv tile transposed: [d][e]
    const int t = threadIdx.x;
    const int lane = t & 63;
    const int w = t >> 6;
    const int wr = w >> 1, wc = w & 1;
    const int brow = blockIdx.y * 64;   // o
    const int bcol = blockIdx.x * 64;   // d

    f32x4 acc[2][2];
#pragma unroll
    for (int m = 0; m < 2; ++m)
#pragma unroll
        for (int n = 0; n < 2; ++n) acc[m][n] = (f32x4)(0.0f);

    for (int kt = 0; kt < 32; ++kt) {
        const float* ga = Wo + (size_t)(brow + (t >> 2)) * D_MODEL + kt * 32 + (t & 3) * 8;
        float4 a0 = *(const float4*)ga;
        float4 a1 = *(const float4*)(ga + 4);
        float4 bv[2];
#pragma unroll
        for (int j = 0; j < 2; ++j) {
            int lin = j * 256 + t;
            int e = lin >> 4, c4 = lin & 15;
            bv[j] = *(const float4*)(Wv + (size_t)(kt * 32 + e) * D_MODEL + bcol + c4 * 4);
        }
        *reinterpret_cast<short8*>(&Ash[t >> 2][(t & 3) * 8]) = cvt8(a0, a1);
#pragma unroll
        for (int j = 0; j < 2; ++j) {
            int lin = j * 256 + t;
            int e = lin >> 4, c4 = lin & 15;
            int d = c4 * 4;
            Bsh[d + 0][e] = f2bf(bv[j].x);
            Bsh[d + 1][e] = f2bf(bv[j].y);
            Bsh[d + 2][e] = f2bf(bv[j].z);
            Bsh[d + 3][e] = f2bf(bv[j].w);
        }
        __syncthreads();
        {
            const int r = lane & 15, q = lane >> 4;
            short8 af[2], bfr[2];
#pragma unroll
            for (int m = 0; m < 2; ++m)
                af[m] = *reinterpret_cast<const short8*>(&Ash[wr * 32 + m * 16 + r][q * 8]);
#pragma unroll
            for (int n = 0; n < 2; ++n)
                bfr[n] = *reinterpret_cast<const short8*>(&Bsh[wc * 32 + n * 16 + r][q * 8]);
#pragma unroll
            for (int m = 0; m < 2; ++m)
#pragma unroll
                for (int n = 0; n < 2; ++n)
                    acc[m][n] = __builtin_amdgcn_mfma_f32_16x16x32_bf16(
                        af[m], bfr[n], acc[m][n], 0, 0, 0);
        }
        __syncthreads();
    }

    const int r = lane & 15, q = lane >> 4;
#pragma unroll
    for (int m = 0; m < 2; ++m)
#pragma unroll
        for (int n = 0; n < 2; ++n)
#pragma unroll
            for (int j = 0; j < 4; ++j) {
                int o = brow + wr * 32 + m * 16 + q * 4 + j;     // C/D: row=(l>>4)*4+j
                int d = bcol + wc * 32 + n * 16 + r;             //      col=l&15
                Cw[(size_t)o * D_MODEL + d] = f2bf(acc[m][n][j]);
            }
}

// ---------------- Kernel 2: 128x128 / BK=64 / 8 waves / 2-barrier ----------------
__global__ __launch_bounds__(512, 4) void attn_gemm_kernel(
        const float* __restrict__ kv, const float* __restrict__ query,
        const short* __restrict__ Cw, const float* __restrict__ bo,
        float* __restrict__ out) {
    // A: 128 x 64 f32 (16 chunks of 16B/row), XOR-swizzled via glds SOURCE (32 KB).
    // B: 128 x 64 bf16 (8 chunks/row), XOR-swizzled via glds SOURCE (16 KB).
    // Read chunk c of row at position c^(row&7). Single-buffered, 48 KB.
    __shared__ __align__(16) float Afs[128][64];
    __shared__ __align__(16) short Bsh[128][64];
    const int t = threadIdx.x;
    const int lane = t & 63;
    const int w = t >> 6;                    // 8 waves
    const int wm = w >> 2, wn = w & 3;       // 2 x 4 wave grid
    const int r = lane & 15, q = lane >> 4;

    // XCD swizzle: XCD = L % 8; 8 o-tiles of one row-tile share an XCD ->
    // kv L2-reused 8x (proven r8: FETCH 574->141 MB).
    const int L = blockIdx.x;
    const int x = L & 7, j5 = L >> 3;
    const int bx = j5 & 7;                   // o-tile (0..7)
    const int rt = (j5 >> 3) * 8 + x;        // row-tile (0..255)
    const int brow = rt * 128;

    f32x4 acc[4][2];
#pragma unroll
    for (int m = 0; m < 4; ++m)
#pragma unroll
        for (int n = 0; n < 2; ++n) acc[m][n] = (f32x4)(0.0f);

    for (int kt = 0; kt < 16; ++kt) {
        // stage A: 32 KB = 2048 chunks of 16B; 512 threads -> 4 glds issues.
#pragma unroll
        for (int i = 0; i < 4; ++i) {
            int chunk = i * 512 + t;
            int rl = chunk >> 4, d = chunk & 15;
            int cs = d ^ (rl & 7);
            const float* g = kv + (size_t)(brow + rl) * D_MODEL + kt * 64 + cs * 4;
            __builtin_amdgcn_global_load_lds(
                (const __attribute__((address_space(1))) void*)g,
                (__attribute__((address_space(3))) void*)
                    ((char*)&Afs[0][0] + i * 8192 + w * 1024),
                16, 0, 0);
        }
        // stage B: 16 KB = 1024 chunks; 2 glds issues.
#pragma unroll
        for (int i = 0; i < 2; ++i) {
            int chunk = i * 512 + t;
            int rl = chunk >> 3, d = chunk & 7;
            int cs = d ^ (rl & 7);
            const short* g = Cw + (size_t)(bx * 128 + rl) * D_MODEL + kt * 64 + cs * 8;
            __builtin_amdgcn_global_load_lds(
                (const __attribute__((address_space(1))) void*)g,
                (__attribute__((address_space(3))) void*)
                    ((char*)&Bsh[0][0] + i * 8192 + w * 1024),
                16, 0, 0);
        }
        __syncthreads();   // implicit drain: LDS valid
#pragma unroll
        for (int s = 0; s < 2; ++s) {
            short8 af[4], bfr[2];
#pragma unroll
            for (int m = 0; m < 4; ++m) {
                int row = wm * 64 + m * 16 + r;
                int c0 = (s * 8 + q * 2) ^ (row & 7);
                int c1 = (s * 8 + q * 2 + 1) ^ (row & 7);
                float4 lo = *(const float4*)&Afs[row][c0 * 4];
                float4 hi = *(const float4*)&Afs[row][c1 * 4];
                af[m] = cvt8(lo, hi);                 // pk cvt under MFMA
            }
#pragma unroll
            for (int n = 0; n < 2; ++n) {
                int row = wn * 32 + n * 16 + r;
                int c = (s * 4 + q) ^ (row & 7);
                bfr[n] = *reinterpret_cast<const short8*>(&Bsh[row][c * 8]);
            }
#pragma unroll
            for (int m = 0; m < 4; ++m)
#pragma unroll
                for (int n = 0; n < 2; ++n)
                    acc[m][n] = __builtin_amdgcn_mfma_f32_16x16x32_bf16(
                        af[m], bfr[n], acc[m][n], 0, 0, 0);
        }
        __syncthreads();
    }

    // epilogue: + bo + query residual, f32 store
#pragma unroll
    for (int n = 0; n < 2; ++n) {
        int o = bx * 128 + wn * 32 + n * 16 + r;
        float bov = bo[o];
#pragma unroll
        for (int m = 0; m < 4; ++m) {
            int gb = brow + wm * 64 + m * 16 + q * 4;
#pragma unroll
            for (int j = 0; j < 4; ++j) {
                int grow = gb + j;
                out[(size_t)grow * D_MODEL + o] =
                    acc[m][n][j] + bov +
                    query[(size_t)(grow & (BATCH - 1)) * D_MODEL + o];
            }
        }
    }
}

extern "C" void kernel_launch(void* const* d_in, const int* in_sizes, int n_in,
                              void* d_out, int out_size, void* d_ws, size_t ws_size,
                              hipStream_t stream) {
    // Robust input classification by element count (falls back to dict order):
    int kv_i = 1, q_i = 0, bo_i = 6;
    int w_i[4] = {2, 3, 4, 5};
    int nw = 0;
    for (int i = 0; i < n_in; ++i) {
        long s = in_sizes[i];
        if (s == 33554432) kv_i = i;
        else if (s == 4194304) q_i = i;
        else if (s == 1024) bo_i = i;
        else if (s == 1048576 && nw < 4) w_i[nw++] = i;
    }
    const float* query = (const float*)d_in[q_i];
    const float* kv    = (const float*)d_in[kv_i];
    const float* Wv    = (const float*)d_in[w_i[2]];
    const float* Wo    = (const float*)d_in[w_i[3]];
    const float* bo    = (const float*)d_in[bo_i];
    short* Cw  = (short*)d_ws;              // 1024*1024 bf16 = 2 MB
    float* out = (float*)d_out;             // f32 output

    fuse_w_kernel<<<dim3(16, 16), dim3(256), 0, stream>>>(Wo, Wv, Cw);
    attn_gemm_kernel<<<dim3(2048), dim3(512), 0, stream>>>(kv, query, Cw, bo, out);
}

// Round 19
// 194.629 us; speedup vs baseline: 1.2124x; 1.1193x over previous
//
#include <hip/hip_runtime.h>
#include <hip/hip_bf16.h>

// out[m,b,:] = kv[m,b,:] @ W + bo + query[b,:],  W = (Wo@Wv) row o, col d
// (softmax over size-1 axis == 1 -> ones; q/k/Wq/Wk dead). f32 output.
// K1: Cw = Wo@Wv, MFMA bf16 (proven r9). ~3us.
// PRE: kv f32 -> bf16 (d_ws), ~37us. Enables a 12KB K-tile.
// K2 (bf16 path): 3-stage glds pipeline, BK=32, counted vmcnt(6) across raw
//     barriers — tiles kt+1,kt+2 stay in flight through compute(kt). glds-
//     pure loop (no reg-staged loads -> no r10 asm-island risk); 36KB LDS ->
//     4 blocks/CU (fixes r17's occupancy failure). 64x128 tile, XOR swizzle
//     both tiles, XCD swizzle (proven r8/r15/r16).
// Fallback (ws < 69.2MB): r15 kernel verbatim (167us proven).

typedef __attribute__((ext_vector_type(4))) float f32x4;
typedef __attribute__((ext_vector_type(8))) short short8;

#define D_MODEL 1024
#define BATCH   4096
#define M_ROWS  32768   // 8 * 4096

__device__ __forceinline__ short f2bf(float f) {
    union { float f; unsigned u; } x; x.f = f;
    unsigned r = (x.u + 0x7fffu + ((x.u >> 16) & 1u)) >> 16;   // RNE
    return (short)r;
}

__device__ __forceinline__ unsigned bfpk(float lo, float hi) {
    __hip_bfloat162 h = __float22bfloat162_rn(make_float2(lo, hi));  // v_cvt_pk_bf16_f32
    unsigned u; __builtin_memcpy(&u, &h, 4); return u;
}

__device__ __forceinline__ short8 cvt8(float4 a, float4 b) {
    union { unsigned u[4]; short8 s; } r;
    r.u[0] = bfpk(a.x, a.y);
    r.u[1] = bfpk(a.z, a.w);
    r.u[2] = bfpk(b.x, b.y);
    r.u[3] = bfpk(b.z, b.w);
    return r.s;
}

// ---------------- Prepass: kv f32 -> bf16 ----------------
__global__ __launch_bounds__(256) void cvt_kv_kernel(
        const float* __restrict__ in, short* __restrict__ outb) {
    const long n8 = (long)M_ROWS * D_MODEL / 8;     // 4194304 groups of 8
    long i = (long)blockIdx.x * 256 + threadIdx.x;
    const long stride = (long)gridDim.x * 256;
    for (; i < n8; i += stride) {
        const float4* p = (const float4*)(in + i * 8);
        float4 a = p[0], b = p[1];
        *reinterpret_cast<short8*>(outb + i * 8) = cvt8(a, b);
    }
}

// ---------------- Kernel 1: fuse weights Cw = Wo @ Wv (bf16, MFMA, 64x64) ----------------
__global__ __launch_bounds__(256) void fuse_w_kernel(
        const float* __restrict__ Wo, const float* __restrict__ Wv,
        short* __restrict__ Cw) {
    __shared__ __align__(16) short Ash[64][32];
    __shared__ __align__(16) short Bsh[64][32];
    const int t = threadIdx.x;
    const int lane = t & 63;
    const int w = t >> 6;
    const int wr = w >> 1, wc = w & 1;
    const int brow = blockIdx.y * 64;   // o
    const int bcol = blockIdx.x * 64;   // d

    f32x4 acc[2][2];
#pragma unroll
    for (int m = 0; m < 2; ++m)
#pragma unroll
        for (int n = 0; n < 2; ++n) acc[m][n] = (f32x4)(0.0f);

    for (int kt = 0; kt < 32; ++kt) {
        const float* ga = Wo + (size_t)(brow + (t >> 2)) * D_MODEL + kt * 32 + (t & 3) * 8;
        float4 a0 = *(const float4*)ga;
        float4 a1 = *(const float4*)(ga + 4);
        float4 bv[2];
#pragma unroll
        for (int j = 0; j < 2; ++j) {
            int lin = j * 256 + t;
            int e = lin >> 4, c4 = lin & 15;
            bv[j] = *(const float4*)(Wv + (size_t)(kt * 32 + e) * D_MODEL + bcol + c4 * 4);
        }
        *reinterpret_cast<short8*>(&Ash[t >> 2][(t & 3) * 8]) = cvt8(a0, a1);
#pragma unroll
        for (int j = 0; j < 2; ++j) {
            int lin = j * 256 + t;
            int e = lin >> 4, c4 = lin & 15;
            int d = c4 * 4;
            Bsh[d + 0][e] = f2bf(bv[j].x);
            Bsh[d + 1][e] = f2bf(bv[j].y);
            Bsh[d + 2][e] = f2bf(bv[j].z);
            Bsh[d + 3][e] = f2bf(bv[j].w);
        }
        __syncthreads();
        {
            const int r = lane & 15, q = lane >> 4;
            short8 af[2], bfr[2];
#pragma unroll
            for (int m = 0; m < 2; ++m)
                af[m] = *reinterpret_cast<const short8*>(&Ash[wr * 32 + m * 16 + r][q * 8]);
#pragma unroll
            for (int n = 0; n < 2; ++n)
                bfr[n] = *reinterpret_cast<const short8*>(&Bsh[wc * 32 + n * 16 + r][q * 8]);
#pragma unroll
            for (int m = 0; m < 2; ++m)
#pragma unroll
                for (int n = 0; n < 2; ++n)
                    acc[m][n] = __builtin_amdgcn_mfma_f32_16x16x32_bf16(
                        af[m], bfr[n], acc[m][n], 0, 0, 0);
        }
        __syncthreads();
    }

    const int r = lane & 15, q = lane >> 4;
#pragma unroll
    for (int m = 0; m < 2; ++m)
#pragma unroll
        for (int n = 0; n < 2; ++n)
#pragma unroll
            for (int j = 0; j < 4; ++j) {
                int o = brow + wr * 32 + m * 16 + q * 4 + j;
                int d = bcol + wc * 32 + n * 16 + r;
                Cw[(size_t)o * D_MODEL + d] = f2bf(acc[m][n][j]);
            }
}

// ---------------- Kernel 2 (bf16): 3-stage counted-vmcnt pipeline, BK=32 ----------------
__global__ __launch_bounds__(256, 4) void attn_gemm_bf16(
        const short* __restrict__ kvb, const float* __restrict__ query,
        const short* __restrict__ Cw, const float* __restrict__ bo,
        float* __restrict__ out) {
    // Per K-tile (BK=32): A 64x32 bf16 = 4KB (1 glds), B 128x32 bf16 = 8KB
    // (2 glds). 3 buffers = 36KB. XOR swizzle chunk^=(row&3) both-sides.
    __shared__ __align__(16) short Afs[3][64][32];
    __shared__ __align__(16) short Bsh[3][128][32];
    const int t = threadIdx.x;
    const int lane = t & 63;
    const int w = t >> 6;
    const int wr = w >> 1, wc = w & 1;
    const int r = lane & 15, q = lane >> 4;

    // XCD swizzle (proven r8): 8 o-tiles of one row-tile share L%8.
    const int L = blockIdx.x;
    const int x = L & 7, j5 = L >> 3;
    const int bx = j5 & 7;                   // o-tile (0..7)
    const int rt = (j5 >> 3) * 8 + x;        // row-tile (0..511)
    const int brow = rt * 64;

    f32x4 acc[2][4];
#pragma unroll
    for (int m = 0; m < 2; ++m)
#pragma unroll
        for (int n = 0; n < 4; ++n) acc[m][n] = (f32x4)(0.0f);

    auto stage = [&](int kt, int buf) {      // 3 glds, no VGPR results
        {   // A: 4KB, 1 issue. chunk=t: row=t>>2, dest d=t&3, src cs=d^(row&3)
            int rl = t >> 2, d = t & 3;
            int cs = d ^ (rl & 3);
            const short* g = kvb + (size_t)(brow + rl) * D_MODEL + kt * 32 + cs * 8;
            __builtin_amdgcn_global_load_lds(
                (const __attribute__((address_space(1))) void*)g,
                (__attribute__((address_space(3))) void*)
                    ((char*)&Afs[buf][0][0] + w * 1024),
                16, 0, 0);
        }
#pragma unroll
        for (int i = 0; i < 2; ++i) {        // B: 8KB, 2 issues
            int chunk = i * 256 + t;
            int rl = chunk >> 2, d = chunk & 3;
            int cs = d ^ (rl & 3);
            const short* g = Cw + (size_t)(bx * 128 + rl) * D_MODEL + kt * 32 + cs * 8;
            __builtin_amdgcn_global_load_lds(
                (const __attribute__((address_space(1))) void*)g,
                (__attribute__((address_space(3))) void*)
                    ((char*)&Bsh[buf][0][0] + i * 4096 + w * 1024),
                16, 0, 0);
        }
    };
    auto compute = [&](int buf) {
        short8 af[2], bfr[4];
#pragma unroll
        for (int m = 0; m < 2; ++m) {
            int row = wr * 32 + m * 16 + r;
            int c = q ^ (row & 3);
            af[m] = *reinterpret_cast<const short8*>(&Afs[buf][row][c * 8]);
        }
#pragma unroll
        for (int n = 0; n < 4; ++n) {
            int row = wc * 64 + n * 16 + r;
            int c = q ^ (row & 3);
            bfr[n] = *reinterpret_cast<const short8*>(&Bsh[buf][row][c * 8]);
        }
#pragma unroll
        for (int m = 0; m < 2; ++m)
#pragma unroll
            for (int n = 0; n < 4; ++n)
                acc[m][n] = __builtin_amdgcn_mfma_f32_16x16x32_bf16(
                    af[m], bfr[n], acc[m][n], 0, 0, 0);
    };

    // prologue: tiles 0,1 in flight (6 glds)
    stage(0, 0);
    stage(1, 1);
    for (int kt = 0; kt < 32; ++kt) {
        const int bsel = kt % 3;
        if (kt < 30) {
            stage(kt + 2, (kt + 2) % 3);     // 9 outstanding
            asm volatile("s_waitcnt vmcnt(6)" ::: "memory");   // kt landed
        } else if (kt == 30) {
            asm volatile("s_waitcnt vmcnt(3)" ::: "memory");
        } else {
            asm volatile("s_waitcnt vmcnt(0)" ::: "memory");
        }
        __builtin_amdgcn_s_barrier();        // all waves' kt-writes visible
        compute(bsel);                       // kt+1, kt+2 glds still flying
        __builtin_amdgcn_s_barrier();        // reads done before buf reuse
    }

    // epilogue: + bo + query residual, f32 store
#pragma unroll
    for (int n = 0; n < 4; ++n) {
        int o = bx * 128 + wc * 64 + n * 16 + r;
        float bov = bo[o];
#pragma unroll
        for (int m = 0; m < 2; ++m) {
            int gb = brow + wr * 32 + m * 16 + q * 4;
#pragma unroll
            for (int j = 0; j < 4; ++j) {
                int grow = gb + j;
                out[(size_t)grow * D_MODEL + o] =
                    acc[m][n][j] + bov +
                    query[(size_t)(grow & (BATCH - 1)) * D_MODEL + o];
            }
        }
    }
}

// ---------------- Kernel 2 fallback (f32 A): r15 verbatim ----------------
__global__ __launch_bounds__(256, 4) void attn_gemm_f32(
        const float* __restrict__ kv, const float* __restrict__ query,
        const short* __restrict__ Cw, const float* __restrict__ bo,
        float* __restrict__ out) {
    __shared__ __align__(16) float Afs[64][64];
    __shared__ __align__(16) short Bsh[128][64];
    const int t = threadIdx.x;
    const int lane = t & 63;
    const int w = t >> 6;
    const int wr = w >> 1, wc = w & 1;
    const int r = lane & 15, q = lane >> 4;

    const int L = blockIdx.x;
    const int x = L & 7, j5 = L >> 3;
    const int bx = j5 & 7;
    const int rt = (j5 >> 3) * 8 + x;
    const int brow = rt * 64;

    f32x4 acc[2][4];
#pragma unroll
    for (int m = 0; m < 2; ++m)
#pragma unroll
        for (int n = 0; n < 4; ++n) acc[m][n] = (f32x4)(0.0f);

    for (int kt = 0; kt < 16; ++kt) {
#pragma unroll
        for (int i = 0; i < 4; ++i) {
            int chunk = i * 256 + t;
            int rl = chunk >> 4, d = chunk & 15;
            int cs = d ^ (rl & 7);
            const float* g = kv + (size_t)(brow + rl) * D_MODEL + kt * 64 + cs * 4;
            __builtin_amdgcn_global_load_lds(
                (const __attribute__((address_space(1))) void*)g,
                (__attribute__((address_space(3))) void*)
                    ((char*)&Afs[0][0] + i * 4096 + w * 1024),
                16, 0, 0);
        }
#pragma unroll
        for (int i = 0; i < 4; ++i) {
            int chunk = i * 256 + t;
            int rl = chunk >> 3, d = chunk & 7;
            int cs = d ^ (rl & 7);
            const short* g = Cw + (size_t)(bx * 128 + rl) * D_MODEL + kt * 64 + cs * 8;
            __builtin_amdgcn_global_load_lds(
                (const __attribute__((address_space(1))) void*)g,
                (__attribute__((address_space(3))) void*)
                    ((char*)&Bsh[0][0] + i * 4096 + w * 1024),
                16, 0, 0);
        }
        __syncthreads();
#pragma unroll
        for (int s = 0; s < 2; ++s) {
            short8 af[2], bfr[4];
#pragma unroll
            for (int m = 0; m < 2; ++m) {
                int row = wr * 32 + m * 16 + r;
                int c0 = (s * 8 + q * 2) ^ (row & 7);
                int c1 = (s * 8 + q * 2 + 1) ^ (row & 7);
                float4 lo = *(const float4*)&Afs[row][c0 * 4];
                float4 hi = *(const float4*)&Afs[row][c1 * 4];
                af[m] = cvt8(lo, hi);
            }
#pragma unroll
            for (int n = 0; n < 4; ++n) {
                int row = wc * 64 + n * 16 + r;
                int c = (s * 4 + q) ^ (row & 7);
                bfr[n] = *reinterpret_cast<const short8*>(&Bsh[row][c * 8]);
            }
#pragma unroll
            for (int m = 0; m < 2; ++m)
#pragma unroll
                for (int n = 0; n < 4; ++n)
                    acc[m][n] = __builtin_amdgcn_mfma_f32_16x16x32_bf16(
                        af[m], bfr[n], acc[m][n], 0, 0, 0);
        }
        __syncthreads();
    }

#pragma unroll
    for (int n = 0; n < 4; ++n) {
        int o = bx * 128 + wc * 64 + n * 16 + r;
        float bov = bo[o];
#pragma unroll
        for (int m = 0; m < 2; ++m) {
            int gb = brow + wr * 32 + m * 16 + q * 4;
#pragma unroll
            for (int j = 0; j < 4; ++j) {
                int grow = gb + j;
                out[(size_t)grow * D_MODEL + o] =
                    acc[m][n][j] + bov +
                    query[(size_t)(grow & (BATCH - 1)) * D_MODEL + o];
            }
        }
    }
}

extern "C" void kernel_launch(void* const* d_in, const int* in_sizes, int n_in,
                              void* d_out, int out_size, void* d_ws, size_t ws_size,
                              hipStream_t stream) {
    int kv_i = 1, q_i = 0, bo_i = 6;
    int w_i[4] = {2, 3, 4, 5};
    int nw = 0;
    for (int i = 0; i < n_in; ++i) {
        long s = in_sizes[i];
        if (s == 33554432) kv_i = i;
        else if (s == 4194304) q_i = i;
        else if (s == 1024) bo_i = i;
        else if (s == 1048576 && nw < 4) w_i[nw++] = i;
    }
    const float* query = (const float*)d_in[q_i];
    const float* kv    = (const float*)d_in[kv_i];
    const float* Wv    = (const float*)d_in[w_i[2]];
    const float* Wo    = (const float*)d_in[w_i[3]];
    const float* bo    = (const float*)d_in[bo_i];
    short* Cw  = (short*)d_ws;                          // 2 MB
    float* out = (float*)d_out;

    fuse_w_kernel<<<dim3(16, 16), dim3(256), 0, stream>>>(Wo, Wv, Cw);

    const size_t need = (size_t)2 * 1024 * 1024 + (size_t)M_ROWS * D_MODEL * 2;
    if (ws_size >= need) {
        short* kvb = (short*)((char*)d_ws + 2 * 1024 * 1024);   // 67 MB
        cvt_kv_kernel<<<dim3(2048), dim3(256), 0, stream>>>(kv, kvb);
        attn_gemm_bf16<<<dim3(4096), dim3(256), 0, stream>>>(kvb, query, Cw, bo, out);
    } else {
        attn_gemm_f32<<<dim3(4096), dim3(256), 0, stream>>>(kv, query, Cw, bo, out);
    }
}

// Round 20
// 183.371 us; speedup vs baseline: 1.2869x; 1.0614x over previous
//
#include <hip/hip_runtime.h>
#include <hip/hip_bf16.h>

// out[m,b,:] = kv[m,b,:] @ W + bo + query[b,:],  W = (Wo@Wv) row o, col d
// (softmax over size-1 axis == 1 -> ones; q/k/Wq/Wk dead). f32 output.
// K1: Cw = Wo@Wv, MFMA bf16 (proven r9). ~3us.
// PRE: kv f32 -> bf16 (d_ws), ~40us. Enables 16KB K-tiles at 128x128.
// K2 (bf16): 128x128 tile / 8 waves / BK=32 / 3-stage counted-vmcnt(4)
//     pipeline (r19-proven structure, tile doubled to halve per-CU step
//     count 512->256) + fixed XOR swizzle chunk^=(row>>1)&3 (r19's row&3
//     made rows 0/4 collide -> 4-way, 12.58M cycles; >>1 gives free 2-way).
// Fallback (ws < 69.2MB): r15 f32 kernel verbatim.

typedef __attribute__((ext_vector_type(4))) float f32x4;
typedef __attribute__((ext_vector_type(8))) short short8;

#define D_MODEL 1024
#define BATCH   4096
#define M_ROWS  32768   // 8 * 4096

__device__ __forceinline__ short f2bf(float f) {
    union { float f; unsigned u; } x; x.f = f;
    unsigned r = (x.u + 0x7fffu + ((x.u >> 16) & 1u)) >> 16;   // RNE
    return (short)r;
}

__device__ __forceinline__ unsigned bfpk(float lo, float hi) {
    __hip_bfloat162 h = __float22bfloat162_rn(make_float2(lo, hi));  // v_cvt_pk_bf16_f32
    unsigned u; __builtin_memcpy(&u, &h, 4); return u;
}

__device__ __forceinline__ short8 cvt8(float4 a, float4 b) {
    union { unsigned u[4]; short8 s; } r;
    r.u[0] = bfpk(a.x, a.y);
    r.u[1] = bfpk(a.z, a.w);
    r.u[2] = bfpk(b.x, b.y);
    r.u[3] = bfpk(b.z, b.w);
    return r.s;
}

// ---------------- Prepass: kv f32 -> bf16 ----------------
__global__ __launch_bounds__(256) void cvt_kv_kernel(
        const float* __restrict__ in, short* __restrict__ outb) {
    const long n8 = (long)M_ROWS * D_MODEL / 8;
    long i = (long)blockIdx.x * 256 + threadIdx.x;
    const long stride = (long)gridDim.x * 256;
    for (; i < n8; i += stride) {
        const float4* p = (const float4*)(in + i * 8);
        float4 a = p[0], b = p[1];
        *reinterpret_cast<short8*>(outb + i * 8) = cvt8(a, b);
    }
}

// ---------------- Kernel 1: fuse weights Cw = Wo @ Wv (bf16, MFMA, 64x64) ----------------
__global__ __launch_bounds__(256) void fuse_w_kernel(
        const float* __restrict__ Wo, const float* __restrict__ Wv,
        short* __restrict__ Cw) {
    __shared__ __align__(16) short Ash[64][32];
    __shared__ __align__(16) short Bsh[64][32];
    const int t = threadIdx.x;
    const int lane = t & 63;
    const int w = t >> 6;
    const int wr = w >> 1, wc = w & 1;
    const int brow = blockIdx.y * 64;   // o
    const int bcol = blockIdx.x * 64;   // d

    f32x4 acc[2][2];
#pragma unroll
    for (int m = 0; m < 2; ++m)
#pragma unroll
        for (int n = 0; n < 2; ++n) acc[m][n] = (f32x4)(0.0f);

    for (int kt = 0; kt < 32; ++kt) {
        const float* ga = Wo + (size_t)(brow + (t >> 2)) * D_MODEL + kt * 32 + (t & 3) * 8;
        float4 a0 = *(const float4*)ga;
        float4 a1 = *(const float4*)(ga + 4);
        float4 bv[2];
#pragma unroll
        for (int j = 0; j < 2; ++j) {
            int lin = j * 256 + t;
            int e = lin >> 4, c4 = lin & 15;
            bv[j] = *(const float4*)(Wv + (size_t)(kt * 32 + e) * D_MODEL + bcol + c4 * 4);
        }
        *reinterpret_cast<short8*>(&Ash[t >> 2][(t & 3) * 8]) = cvt8(a0, a1);
#pragma unroll
        for (int j = 0; j < 2; ++j) {
            int lin = j * 256 + t;
            int e = lin >> 4, c4 = lin & 15;
            int d = c4 * 4;
            Bsh[d + 0][e] = f2bf(bv[j].x);
            Bsh[d + 1][e] = f2bf(bv[j].y);
            Bsh[d + 2][e] = f2bf(bv[j].z);
            Bsh[d + 3][e] = f2bf(bv[j].w);
        }
        __syncthreads();
        {
            const int r = lane & 15, q = lane >> 4;
            short8 af[2], bfr[2];
#pragma unroll
            for (int m = 0; m < 2; ++m)
                af[m] = *reinterpret_cast<const short8*>(&Ash[wr * 32 + m * 16 + r][q * 8]);
#pragma unroll
            for (int n = 0; n < 2; ++n)
                bfr[n] = *reinterpret_cast<const short8*>(&Bsh[wc * 32 + n * 16 + r][q * 8]);
#pragma unroll
            for (int m = 0; m < 2; ++m)
#pragma unroll
                for (int n = 0; n < 2; ++n)
                    acc[m][n] = __builtin_amdgcn_mfma_f32_16x16x32_bf16(
                        af[m], bfr[n], acc[m][n], 0, 0, 0);
        }
        __syncthreads();
    }

    const int r = lane & 15, q = lane >> 4;
#pragma unroll
    for (int m = 0; m < 2; ++m)
#pragma unroll
        for (int n = 0; n < 2; ++n)
#pragma unroll
            for (int j = 0; j < 4; ++j) {
                int o = brow + wr * 32 + m * 16 + q * 4 + j;
                int d = bcol + wc * 32 + n * 16 + r;
                Cw[(size_t)o * D_MODEL + d] = f2bf(acc[m][n][j]);
            }
}

// ---------------- Kernel 2 (bf16): 128x128 / 8 waves / 3-stage counted vmcnt ----------------
__global__ __launch_bounds__(512, 3) void attn_gemm_bf16(
        const short* __restrict__ kvb, const float* __restrict__ query,
        const short* __restrict__ Cw, const float* __restrict__ bo,
        float* __restrict__ out) {
    // Per K-tile (BK=32): A 128x32 bf16 = 8KB (1 glds/thr), B same. 3 stages
    // = 48KB. XOR swizzle chunk^=(row>>1)&3 both-sides (free 2-way residual).
    __shared__ __align__(16) short Afs[3][128][32];
    __shared__ __align__(16) short Bsh[3][128][32];
    const int t = threadIdx.x;
    const int lane = t & 63;
    const int w = t >> 6;                    // 8 waves
    const int wm = w >> 2, wn = w & 3;       // 2 x 4 wave grid
    const int r = lane & 15, q = lane >> 4;

    // XCD swizzle (proven r8): the 8 o-tiles of one row-tile share L%8.
    const int L = blockIdx.x;
    const int x = L & 7, j5 = L >> 3;
    const int bx = j5 & 7;                   // o-tile (0..7)
    const int rt = (j5 >> 3) * 8 + x;        // row-tile (0..255)
    const int brow = rt * 128;

    f32x4 acc[4][2];
#pragma unroll
    for (int m = 0; m < 4; ++m)
#pragma unroll
        for (int n = 0; n < 2; ++n) acc[m][n] = (f32x4)(0.0f);

    auto stage = [&](int kt, int buf) {      // 2 glds/thread, no VGPR results
        {   // A: 8KB. chunk=t: row=t>>2, dest d=t&3, src cs=d^((row>>1)&3)
            int rl = t >> 2, d = t & 3;
            int cs = d ^ ((rl >> 1) & 3);
            const short* g = kvb + (size_t)(brow + rl) * D_MODEL + kt * 32 + cs * 8;
            __builtin_amdgcn_global_load_lds(
                (const __attribute__((address_space(1))) void*)g,
                (__attribute__((address_space(3))) void*)
                    ((char*)&Afs[buf][0][0] + w * 1024),
                16, 0, 0);
        }
        {   // B: 8KB, same mapping
            int rl = t >> 2, d = t & 3;
            int cs = d ^ ((rl >> 1) & 3);
            const short* g = Cw + (size_t)(bx * 128 + rl) * D_MODEL + kt * 32 + cs * 8;
            __builtin_amdgcn_global_load_lds(
                (const __attribute__((address_space(1))) void*)g,
                (__attribute__((address_space(3))) void*)
                    ((char*)&Bsh[buf][0][0] + w * 1024),
                16, 0, 0);
        }
    };
    auto compute = [&](int buf) {
        short8 af[4], bfr[2];
#pragma unroll
        for (int m = 0; m < 4; ++m) {
            int row = wm * 64 + m * 16 + r;
            int c = q ^ ((row >> 1) & 3);
            af[m] = *reinterpret_cast<const short8*>(&Afs[buf][row][c * 8]);
        }
#pragma unroll
        for (int n = 0; n < 2; ++n) {
            int row = wn * 32 + n * 16 + r;
            int c = q ^ ((row >> 1) & 3);
            bfr[n] = *reinterpret_cast<const short8*>(&Bsh[buf][row][c * 8]);
        }
#pragma unroll
        for (int m = 0; m < 4; ++m)
#pragma unroll
            for (int n = 0; n < 2; ++n)
                acc[m][n] = __builtin_amdgcn_mfma_f32_16x16x32_bf16(
                    af[m], bfr[n], acc[m][n], 0, 0, 0);
    };

    // prologue: tiles 0,1 in flight (4 glds/thread)
    stage(0, 0);
    stage(1, 1);
    for (int kt = 0; kt < 32; ++kt) {
        const int bsel = kt % 3;
        if (kt < 30) {
            stage(kt + 2, (kt + 2) % 3);     // 6 outstanding
            asm volatile("s_waitcnt vmcnt(4)" ::: "memory");   // kt's 2 landed
        } else if (kt == 30) {
            asm volatile("s_waitcnt vmcnt(2)" ::: "memory");
        } else {
            asm volatile("s_waitcnt vmcnt(0)" ::: "memory");
        }
        __builtin_amdgcn_s_barrier();        // all waves' kt-writes visible
        compute(bsel);                       // kt+1, kt+2 glds still flying
        __builtin_amdgcn_s_barrier();        // reads done before buf reuse
    }

    // epilogue: + bo + query residual, f32 store
#pragma unroll
    for (int n = 0; n < 2; ++n) {
        int o = bx * 128 + wn * 32 + n * 16 + r;
        float bov = bo[o];
#pragma unroll
        for (int m = 0; m < 4; ++m) {
            int gb = brow + wm * 64 + m * 16 + q * 4;
#pragma unroll
            for (int j = 0; j < 4; ++j) {
                int grow = gb + j;
                out[(size_t)grow * D_MODEL + o] =
                    acc[m][n][j] + bov +
                    query[(size_t)(grow & (BATCH - 1)) * D_MODEL + o];
            }
        }
    }
}

// ---------------- Kernel 2 fallback (f32 A): r15 verbatim ----------------
__global__ __launch_bounds__(256, 4) void attn_gemm_f32(
        const float* __restrict__ kv, const float* __restrict__ query,
        const short* __restrict__ Cw, const float* __restrict__ bo,
        float* __restrict__ out) {
    __shared__ __align__(16) float Afs[64][64];
    __shared__ __align__(16) short Bsh[128][64];
    const int t = threadIdx.x;
    const int lane = t & 63;
    const int w = t >> 6;
    const int wr = w >> 1, wc = w & 1;
    const int r = lane & 15, q = lane >> 4;

    const int L = blockIdx.x;
    const int x = L & 7, j5 = L >> 3;
    const int bx = j5 & 7;
    const int rt = (j5 >> 3) * 8 + x;
    const int brow = rt * 64;

    f32x4 acc[2][4];
#pragma unroll
    for (int m = 0; m < 2; ++m)
#pragma unroll
        for (int n = 0; n < 4; ++n) acc[m][n] = (f32x4)(0.0f);

    for (int kt = 0; kt < 16; ++kt) {
#pragma unroll
        for (int i = 0; i < 4; ++i) {
            int chunk = i * 256 + t;
            int rl = chunk >> 4, d = chunk & 15;
            int cs = d ^ (rl & 7);
            const float* g = kv + (size_t)(brow + rl) * D_MODEL + kt * 64 + cs * 4;
            __builtin_amdgcn_global_load_lds(
                (const __attribute__((address_space(1))) void*)g,
                (__attribute__((address_space(3))) void*)
                    ((char*)&Afs[0][0] + i * 4096 + w * 1024),
                16, 0, 0);
        }
#pragma unroll
        for (int i = 0; i < 4; ++i) {
            int chunk = i * 256 + t;
            int rl = chunk >> 3, d = chunk & 7;
            int cs = d ^ (rl & 7);
            const short* g = Cw + (size_t)(bx * 128 + rl) * D_MODEL + kt * 64 + cs * 8;
            __builtin_amdgcn_global_load_lds(
                (const __attribute__((address_space(1))) void*)g,
                (__attribute__((address_space(3))) void*)
                    ((char*)&Bsh[0][0] + i * 4096 + w * 1024),
                16, 0, 0);
        }
        __syncthreads();
#pragma unroll
        for (int s = 0; s < 2; ++s) {
            short8 af[2], bfr[4];
#pragma unroll
            for (int m = 0; m < 2; ++m) {
                int row = wr * 32 + m * 16 + r;
                int c0 = (s * 8 + q * 2) ^ (row & 7);
                int c1 = (s * 8 + q * 2 + 1) ^ (row & 7);
                float4 lo = *(const float4*)&Afs[row][c0 * 4];
                float4 hi = *(const float4*)&Afs[row][c1 * 4];
                af[m] = cvt8(lo, hi);
            }
#pragma unroll
            for (int n = 0; n < 4; ++n) {
                int row = wc * 64 + n * 16 + r;
                int c = (s * 4 + q) ^ (row & 7);
                bfr[n] = *reinterpret_cast<const short8*>(&Bsh[row][c * 8]);
            }
#pragma unroll
            for (int m = 0; m < 2; ++m)
#pragma unroll
                for (int n = 0; n < 4; ++n)
                    acc[m][n] = __builtin_amdgcn_mfma_f32_16x16x32_bf16(
                        af[m], bfr[n], acc[m][n], 0, 0, 0);
        }
        __syncthreads();
    }

#pragma unroll
    for (int n = 0; n < 4; ++n) {
        int o = bx * 128 + wc * 64 + n * 16 + r;
        float bov = bo[o];
#pragma unroll
        for (int m = 0; m < 2; ++m) {
            int gb = brow + wr * 32 + m * 16 + q * 4;
#pragma unroll
            for (int j = 0; j < 4; ++j) {
                int grow = gb + j;
                out[(size_t)grow * D_MODEL + o] =
                    acc[m][n][j] + bov +
                    query[(size_t)(grow & (BATCH - 1)) * D_MODEL + o];
            }
        }
    }
}

extern "C" void kernel_launch(void* const* d_in, const int* in_sizes, int n_in,
                              void* d_out, int out_size, void* d_ws, size_t ws_size,
                              hipStream_t stream) {
    int kv_i = 1, q_i = 0, bo_i = 6;
    int w_i[4] = {2, 3, 4, 5};
    int nw = 0;
    for (int i = 0; i < n_in; ++i) {
        long s = in_sizes[i];
        if (s == 33554432) kv_i = i;
        else if (s == 4194304) q_i = i;
        else if (s == 1024) bo_i = i;
        else if (s == 1048576 && nw < 4) w_i[nw++] = i;
    }
    const float* query = (const float*)d_in[q_i];
    const float* kv    = (const float*)d_in[kv_i];
    const float* Wv    = (const float*)d_in[w_i[2]];
    const float* Wo    = (const float*)d_in[w_i[3]];
    const float* bo    = (const float*)d_in[bo_i];
    short* Cw  = (short*)d_ws;                          // 2 MB
    float* out = (float*)d_out;

    fuse_w_kernel<<<dim3(16, 16), dim3(256), 0, stream>>>(Wo, Wv, Cw);

    const size_t need = (size_t)2 * 1024 * 1024 + (size_t)M_ROWS * D_MODEL * 2;
    if (ws_size >= need) {
        short* kvb = (short*)((char*)d_ws + 2 * 1024 * 1024);   // 67 MB
        cvt_kv_kernel<<<dim3(2048), dim3(256), 0, stream>>>(kv, kvb);
        attn_gemm_bf16<<<dim3(2048), dim3(512), 0, stream>>>(kvb, query, Cw, bo, out);
    } else {
        attn_gemm_f32<<<dim3(4096), dim3(256), 0, stream>>>(kv, query, Cw, bo, out);
    }
}

// Round 21
// 178.793 us; speedup vs baseline: 1.3198x; 1.0256x over previous
//
#include <hip/hip_runtime.h>
#include <hip/hip_bf16.h>

// out[m,b,:] = kv[m,b,:] @ W + bo + query[b,:],  W = (Wo@Wv) row o, col d
// (softmax over size-1 axis == 1 -> ones; q/k/Wq/Wk dead). f32 output.
// K1: Cw = Wo@Wv, MFMA bf16 (proven r9). ~3us.
// PRE: kv f32 -> bf16 (d_ws), ~37us.
// K2 (bf16): 128x128 / BK=32 / 3-stage counted-vmcnt / 4 waves in 2x2
//     (r20 was 2x4): LDS-read amplification (gm+gn) 6->4, cutting the
//     dominant pipe (LDS ~61us of r20's 118) by 33%. Swizzle (row>>1)&3
//     both-sides (0 conflicts, r20-proven). XCD swizzle (r8-proven).
// Fallback (ws < 69.2MB): r15 f32 kernel verbatim.

typedef __attribute__((ext_vector_type(4))) float f32x4;
typedef __attribute__((ext_vector_type(8))) short short8;

#define D_MODEL 1024
#define BATCH   4096
#define M_ROWS  32768   // 8 * 4096

__device__ __forceinline__ short f2bf(float f) {
    union { float f; unsigned u; } x; x.f = f;
    unsigned r = (x.u + 0x7fffu + ((x.u >> 16) & 1u)) >> 16;   // RNE
    return (short)r;
}

__device__ __forceinline__ unsigned bfpk(float lo, float hi) {
    __hip_bfloat162 h = __float22bfloat162_rn(make_float2(lo, hi));  // v_cvt_pk_bf16_f32
    unsigned u; __builtin_memcpy(&u, &h, 4); return u;
}

__device__ __forceinline__ short8 cvt8(float4 a, float4 b) {
    union { unsigned u[4]; short8 s; } r;
    r.u[0] = bfpk(a.x, a.y);
    r.u[1] = bfpk(a.z, a.w);
    r.u[2] = bfpk(b.x, b.y);
    r.u[3] = bfpk(b.z, b.w);
    return r.s;
}

// ---------------- Prepass: kv f32 -> bf16 ----------------
__global__ __launch_bounds__(256) void cvt_kv_kernel(
        const float* __restrict__ in, short* __restrict__ outb) {
    const long n8 = (long)M_ROWS * D_MODEL / 8;
    long i = (long)blockIdx.x * 256 + threadIdx.x;
    const long stride = (long)gridDim.x * 256;
    for (; i < n8; i += stride) {
        const float4* p = (const float4*)(in + i * 8);
        float4 a = p[0], b = p[1];
        *reinterpret_cast<short8*>(outb + i * 8) = cvt8(a, b);
    }
}

// ---------------- Kernel 1: fuse weights Cw = Wo @ Wv (bf16, MFMA, 64x64) ----------------
__global__ __launch_bounds__(256) void fuse_w_kernel(
        const float* __restrict__ Wo, const float* __restrict__ Wv,
        short* __restrict__ Cw) {
    __shared__ __align__(16) short Ash[64][32];
    __shared__ __align__(16) short Bsh[64][32];
    const int t = threadIdx.x;
    const int lane = t & 63;
    const int w = t >> 6;
    const int wr = w >> 1, wc = w & 1;
    const int brow = blockIdx.y * 64;   // o
    const int bcol = blockIdx.x * 64;   // d

    f32x4 acc[2][2];
#pragma unroll
    for (int m = 0; m < 2; ++m)
#pragma unroll
        for (int n = 0; n < 2; ++n) acc[m][n] = (f32x4)(0.0f);

    for (int kt = 0; kt < 32; ++kt) {
        const float* ga = Wo + (size_t)(brow + (t >> 2)) * D_MODEL + kt * 32 + (t & 3) * 8;
        float4 a0 = *(const float4*)ga;
        float4 a1 = *(const float4*)(ga + 4);
        float4 bv[2];
#pragma unroll
        for (int j = 0; j < 2; ++j) {
            int lin = j * 256 + t;
            int e = lin >> 4, c4 = lin & 15;
            bv[j] = *(const float4*)(Wv + (size_t)(kt * 32 + e) * D_MODEL + bcol + c4 * 4);
        }
        *reinterpret_cast<short8*>(&Ash[t >> 2][(t & 3) * 8]) = cvt8(a0, a1);
#pragma unroll
        for (int j = 0; j < 2; ++j) {
            int lin = j * 256 + t;
            int e = lin >> 4, c4 = lin & 15;
            int d = c4 * 4;
            Bsh[d + 0][e] = f2bf(bv[j].x);
            Bsh[d + 1][e] = f2bf(bv[j].y);
            Bsh[d + 2][e] = f2bf(bv[j].z);
            Bsh[d + 3][e] = f2bf(bv[j].w);
        }
        __syncthreads();
        {
            const int r = lane & 15, q = lane >> 4;
            short8 af[2], bfr[2];
#pragma unroll
            for (int m = 0; m < 2; ++m)
                af[m] = *reinterpret_cast<const short8*>(&Ash[wr * 32 + m * 16 + r][q * 8]);
#pragma unroll
            for (int n = 0; n < 2; ++n)
                bfr[n] = *reinterpret_cast<const short8*>(&Bsh[wc * 32 + n * 16 + r][q * 8]);
#pragma unroll
            for (int m = 0; m < 2; ++m)
#pragma unroll
                for (int n = 0; n < 2; ++n)
                    acc[m][n] = __builtin_amdgcn_mfma_f32_16x16x32_bf16(
                        af[m], bfr[n], acc[m][n], 0, 0, 0);
        }
        __syncthreads();
    }

    const int r = lane & 15, q = lane >> 4;
#pragma unroll
    for (int m = 0; m < 2; ++m)
#pragma unroll
        for (int n = 0; n < 2; ++n)
#pragma unroll
            for (int j = 0; j < 4; ++j) {
                int o = brow + wr * 32 + m * 16 + q * 4 + j;
                int d = bcol + wc * 32 + n * 16 + r;
                Cw[(size_t)o * D_MODEL + d] = f2bf(acc[m][n][j]);
            }
}

// ---------------- Kernel 2 (bf16): 128x128 / 4 waves 2x2 / 3-stage counted vmcnt ----------------
__global__ __launch_bounds__(256, 3) void attn_gemm_bf16(
        const short* __restrict__ kvb, const float* __restrict__ query,
        const short* __restrict__ Cw, const float* __restrict__ bo,
        float* __restrict__ out) {
    // Per K-tile (BK=32): A 128x32 bf16 = 8KB (2 glds/thr), B same. 3 stages
    // = 48KB. XOR swizzle chunk^=(row>>1)&3 both-sides (free 2-way residual).
    __shared__ __align__(16) short Afs[3][128][32];
    __shared__ __align__(16) short Bsh[3][128][32];
    const int t = threadIdx.x;
    const int lane = t & 63;
    const int w = t >> 6;                    // 4 waves
    const int wm = w >> 1, wn = w & 1;       // 2 x 2 wave grid
    const int r = lane & 15, q = lane >> 4;

    // XCD swizzle (proven r8): the 8 o-tiles of one row-tile share L%8.
    const int L = blockIdx.x;
    const int x = L & 7, j5 = L >> 3;
    const int bx = j5 & 7;                   // o-tile (0..7)
    const int rt = (j5 >> 3) * 8 + x;        // row-tile (0..255)
    const int brow = rt * 128;

    f32x4 acc[4][4];
#pragma unroll
    for (int m = 0; m < 4; ++m)
#pragma unroll
        for (int n = 0; n < 4; ++n) acc[m][n] = (f32x4)(0.0f);

    auto stage = [&](int kt, int buf) {      // 4 glds/thread, no VGPR results
#pragma unroll
        for (int i = 0; i < 2; ++i) {        // A: 8KB = 512 chunks, 2 issues
            int chunk = i * 256 + t;
            int rl = chunk >> 2, d = chunk & 3;
            int cs = d ^ ((rl >> 1) & 3);
            const short* g = kvb + (size_t)(brow + rl) * D_MODEL + kt * 32 + cs * 8;
            __builtin_amdgcn_global_load_lds(
                (const __attribute__((address_space(1))) void*)g,
                (__attribute__((address_space(3))) void*)
                    ((char*)&Afs[buf][0][0] + i * 4096 + w * 1024),
                16, 0, 0);
        }
#pragma unroll
        for (int i = 0; i < 2; ++i) {        // B: 8KB, 2 issues
            int chunk = i * 256 + t;
            int rl = chunk >> 2, d = chunk & 3;
            int cs = d ^ ((rl >> 1) & 3);
            const short* g = Cw + (size_t)(bx * 128 + rl) * D_MODEL + kt * 32 + cs * 8;
            __builtin_amdgcn_global_load_lds(
                (const __attribute__((address_space(1))) void*)g,
                (__attribute__((address_space(3))) void*)
                    ((char*)&Bsh[buf][0][0] + i * 4096 + w * 1024),
                16, 0, 0);
        }
    };
    auto compute = [&](int buf) {
        short8 af[4], bfr[4];
#pragma unroll
        for (int m = 0; m < 4; ++m) {
            int row = wm * 64 + m * 16 + r;
            int c = q ^ ((row >> 1) & 3);
            af[m] = *reinterpret_cast<const short8*>(&Afs[buf][row][c * 8]);
        }
#pragma unroll
        for (int n = 0; n < 4; ++n) {
            int row = wn * 64 + n * 16 + r;
            int c = q ^ ((row >> 1) & 3);
            bfr[n] = *reinterpret_cast<const short8*>(&Bsh[buf][row][c * 8]);
        }
#pragma unroll
        for (int m = 0; m < 4; ++m)
#pragma unroll
            for (int n = 0; n < 4; ++n)
                acc[m][n] = __builtin_amdgcn_mfma_f32_16x16x32_bf16(
                    af[m], bfr[n], acc[m][n], 0, 0, 0);
    };

    // prologue: tiles 0,1 in flight (8 glds/thread)
    stage(0, 0);
    stage(1, 1);
    for (int kt = 0; kt < 32; ++kt) {
        const int bsel = kt % 3;
        if (kt < 30) {
            stage(kt + 2, (kt + 2) % 3);     // 12 outstanding max
            asm volatile("s_waitcnt vmcnt(8)" ::: "memory");   // kt's 4 landed
        } else if (kt == 30) {
            asm volatile("s_waitcnt vmcnt(4)" ::: "memory");
        } else {
            asm volatile("s_waitcnt vmcnt(0)" ::: "memory");
        }
        __builtin_amdgcn_s_barrier();        // all waves' kt-writes visible
        compute(bsel);                       // kt+1, kt+2 glds still flying
        __builtin_amdgcn_s_barrier();        // reads done before buf reuse
    }

    // epilogue: + bo + query residual, f32 store
#pragma unroll
    for (int n = 0; n < 4; ++n) {
        int o = bx * 128 + wn * 64 + n * 16 + r;
        float bov = bo[o];
#pragma unroll
        for (int m = 0; m < 4; ++m) {
            int gb = brow + wm * 64 + m * 16 + q * 4;
#pragma unroll
            for (int j = 0; j < 4; ++j) {
                int grow = gb + j;
                out[(size_t)grow * D_MODEL + o] =
                    acc[m][n][j] + bov +
                    query[(size_t)(grow & (BATCH - 1)) * D_MODEL + o];
            }
        }
    }
}

// ---------------- Kernel 2 fallback (f32 A): r15 verbatim ----------------
__global__ __launch_bounds__(256, 4) void attn_gemm_f32(
        const float* __restrict__ kv, const float* __restrict__ query,
        const short* __restrict__ Cw, const float* __restrict__ bo,
        float* __restrict__ out) {
    __shared__ __align__(16) float Afs[64][64];
    __shared__ __align__(16) short Bsh[128][64];
    const int t = threadIdx.x;
    const int lane = t & 63;
    const int w = t >> 6;
    const int wr = w >> 1, wc = w & 1;
    const int r = lane & 15, q = lane >> 4;

    const int L = blockIdx.x;
    const int x = L & 7, j5 = L >> 3;
    const int bx = j5 & 7;
    const int rt = (j5 >> 3) * 8 + x;
    const int brow = rt * 64;

    f32x4 acc[2][4];
#pragma unroll
    for (int m = 0; m < 2; ++m)
#pragma unroll
        for (int n = 0; n < 4; ++n) acc[m][n] = (f32x4)(0.0f);

    for (int kt = 0; kt < 16; ++kt) {
#pragma unroll
        for (int i = 0; i < 4; ++i) {
            int chunk = i * 256 + t;
            int rl = chunk >> 4, d = chunk & 15;
            int cs = d ^ (rl & 7);
            const float* g = kv + (size_t)(brow + rl) * D_MODEL + kt * 64 + cs * 4;
            __builtin_amdgcn_global_load_lds(
                (const __attribute__((address_space(1))) void*)g,
                (__attribute__((address_space(3))) void*)
                    ((char*)&Afs[0][0] + i * 4096 + w * 1024),
                16, 0, 0);
        }
#pragma unroll
        for (int i = 0; i < 4; ++i) {
            int chunk = i * 256 + t;
            int rl = chunk >> 3, d = chunk & 7;
            int cs = d ^ (rl & 7);
            const short* g = Cw + (size_t)(bx * 128 + rl) * D_MODEL + kt * 64 + cs * 8;
            __builtin_amdgcn_global_load_lds(
                (const __attribute__((address_space(1))) void*)g,
                (__attribute__((address_space(3))) void*)
                    ((char*)&Bsh[0][0] + i * 4096 + w * 1024),
                16, 0, 0);
        }
        __syncthreads();
#pragma unroll
        for (int s = 0; s < 2; ++s) {
            short8 af[2], bfr[4];
#pragma unroll
            for (int m = 0; m < 2; ++m) {
                int row = wr * 32 + m * 16 + r;
                int c0 = (s * 8 + q * 2) ^ (row & 7);
                int c1 = (s * 8 + q * 2 + 1) ^ (row & 7);
                float4 lo = *(const float4*)&Afs[row][c0 * 4];
                float4 hi = *(const float4*)&Afs[row][c1 * 4];
                af[m] = cvt8(lo, hi);
            }
#pragma unroll
            for (int n = 0; n < 4; ++n) {
                int row = wc * 64 + n * 16 + r;
                int c = (s * 4 + q) ^ (row & 7);
                bfr[n] = *reinterpret_cast<const short8*>(&Bsh[row][c * 8]);
            }
#pragma unroll
            for (int m = 0; m < 2; ++m)
#pragma unroll
                for (int n = 0; n < 4; ++n)
                    acc[m][n] = __builtin_amdgcn_mfma_f32_16x16x32_bf16(
                        af[m], bfr[n], acc[m][n], 0, 0, 0);
        }
        __syncthreads();
    }

#pragma unroll
    for (int n = 0; n < 4; ++n) {
        int o = bx * 128 + wc * 64 + n * 16 + r;
        float bov = bo[o];
#pragma unroll
        for (int m = 0; m < 2; ++m) {
            int gb = brow + wr * 32 + m * 16 + q * 4;
#pragma unroll
            for (int j = 0; j < 4; ++j) {
                int grow = gb + j;
                out[(size_t)grow * D_MODEL + o] =
                    acc[m][n][j] + bov +
                    query[(size_t)(grow & (BATCH - 1)) * D_MODEL + o];
            }
        }
    }
}

extern "C" void kernel_launch(void* const* d_in, const int* in_sizes, int n_in,
                              void* d_out, int out_size, void* d_ws, size_t ws_size,
                              hipStream_t stream) {
    int kv_i = 1, q_i = 0, bo_i = 6;
    int w_i[4] = {2, 3, 4, 5};
    int nw = 0;
    for (int i = 0; i < n_in; ++i) {
        long s = in_sizes[i];
        if (s == 33554432) kv_i = i;
        else if (s == 4194304) q_i = i;
        else if (s == 1024) bo_i = i;
        else if (s == 1048576 && nw < 4) w_i[nw++] = i;
    }
    const float* query = (const float*)d_in[q_i];
    const float* kv    = (const float*)d_in[kv_i];
    const float* Wv    = (const float*)d_in[w_i[2]];
    const float* Wo    = (const float*)d_in[w_i[3]];
    const float* bo    = (const float*)d_in[bo_i];
    short* Cw  = (short*)d_ws;                          // 2 MB
    float* out = (float*)d_out;

    fuse_w_kernel<<<dim3(16, 16), dim3(256), 0, stream>>>(Wo, Wv, Cw);

    const size_t need = (size_t)2 * 1024 * 1024 + (size_t)M_ROWS * D_MODEL * 2;
    if (ws_size >= need) {
        short* kvb = (short*)((char*)d_ws + 2 * 1024 * 1024);   // 67 MB
        cvt_kv_kernel<<<dim3(2048), dim3(256), 0, stream>>>(kv, kvb);
        attn_gemm_bf16<<<dim3(2048), dim3(256), 0, stream>>>(kvb, query, Cw, bo, out);
    } else {
        attn_gemm_f32<<<dim3(4096), dim3(256), 0, stream>>>(kv, query, Cw, bo, out);
    }
}